// Round 2
// baseline (198.047 us; speedup 1.0000x reference)
//
#include <hip/hip_runtime.h>

typedef unsigned short u16;
typedef unsigned int u32;

using f32x4  = __attribute__((ext_vector_type(4))) float;
using bf16x8 = __attribute__((ext_vector_type(8))) __bf16;

#define DEV __device__ __forceinline__

DEV u16 f2bf(float f) {                       // RTNE f32 -> bf16
  union { float f; u32 u; } x; x.f = f;
  return (u16)((x.u + 0x7fffu + ((x.u >> 16) & 1u)) >> 16);
}
DEV float bf2f(u16 h) {
  union { u32 u; float f; } x; x.u = ((u32)h) << 16;
  return x.f;
}

DEV void async_cp16(const u16* g, u16* l) {   // 16B global -> LDS direct
  __builtin_amdgcn_global_load_lds((const __attribute__((address_space(1))) void*)g,
                                   (__attribute__((address_space(3))) void*)l,
                                   16, 0, 0);
}

static constexpr int BATCH = 4096;
static constexpr int FEAT  = 512;
static constexpr int EMB   = 64;
static constexpr int HID   = 1024;
static constexpr int NC    = 64;
static constexpr int DIN   = 576;   // FEAT + EMB
static constexpr int LIB   = 256;   // LIB_X == LIB_Y == OUT_J

// ---- dtype / index-width detection (deterministic per input, graph-safe) ---
// flags[0]: 1 if float tensors are f32 storage, 0 if bf16 storage.
// flags[1]: option stride in u32 words (2 if int64, 1 if int32).
__global__ __launch_bounds__(256) void detect_k(const u32* __restrict__ state_raw,
                                                const u32* __restrict__ opt_raw,
                                                int* __restrict__ flags) {
  __shared__ int c_ib, c_onz;
  if (threadIdx.x == 0) { c_ib = 0; c_onz = 0; }
  __syncthreads();
  int ib = 0, onz = 0;
  for (int i = threadIdx.x; i < 4096; i += 256) {
    u32 w = state_raw[i];
    u32 e = (w >> 7) & 0xFFu;                 // exponent of low-half-as-bf16
    if (e >= 100 && e <= 142) ib++;
    if ((i & 1) && opt_raw[i] != 0) onz++;
  }
  atomicAdd(&c_ib, ib);
  atomicAdd(&c_onz, onz);
  __syncthreads();
  if (threadIdx.x == 0) {
    flags[0] = (c_ib < 2048) ? 1 : 0;         // low halves not bf16-like -> f32
    flags[1] = (c_onz == 0) ? 2 : 1;          // all odd words zero -> int64
  }
}

// ------------- concat: all_state[b] = [state[b], embed_table[option[b]]] ----
__global__ __launch_bounds__(256) void concat_k(const void* __restrict__ state,
                                                const int* __restrict__ opt,
                                                const void* __restrict__ emb,
                                                u16* __restrict__ all_state,
                                                const int* __restrict__ flags) {
  const int isf32 = flags[0], os = flags[1];
  int t = blockIdx.x * 256 + threadIdx.x;     // BATCH*72 threads, 8 bf16 each
  int b = t / 72, ch = t % 72;
  const void* base;
  size_t srcoff;
  if (ch < 64) { base = state; srcoff = (size_t)b * FEAT + ch * 8; }
  else {
    base = emb;
    srcoff = (size_t)opt[(size_t)b * os] * EMB + (ch - 64) * 8;
  }
  u16 o[8];
  if (isf32) {
    const float* s = (const float*)base + srcoff;
#pragma unroll
    for (int i = 0; i < 8; ++i) o[i] = f2bf(s[i]);
  } else {
    *(uint4*)o = *(const uint4*)((const u16*)base + srcoff);
  }
  *(uint4*)(all_state + (size_t)b * DIN + ch * 8) = *(const uint4*)o;
}

// ------ 32x32 tiled transpose + bf16-ify, out[c][r] = in[r][c], z-batched ---
__global__ __launch_bounds__(256) void transpose_k(const void* __restrict__ in,
                                                   u16* __restrict__ out,
                                                   int R, int C,
                                                   const int* __restrict__ flags) {
  const int isf32 = flags[0];
  __shared__ u16 tile[32][33];
  const size_t base = (size_t)blockIdx.z * R * C;
  const int r0 = blockIdx.y * 32, c0 = blockIdx.x * 32, t = threadIdx.x;
#pragma unroll
  for (int i = 0; i < 4; ++i) {
    int idx = t + i * 256, r = idx >> 5, c = idx & 31;
    size_t off = base + (size_t)(r0 + r) * C + (c0 + c);
    tile[r][c] = isf32 ? f2bf(((const float*)in)[off]) : ((const u16*)in)[off];
  }
  __syncthreads();
#pragma unroll
  for (int i = 0; i < 4; ++i) {
    int idx = t + i * 256, c = idx >> 5, r = idx & 31;
    out[base + (size_t)(c0 + c) * R + (r0 + r)] = tile[r][c];
  }
}

// ------------- counting sort of batch rows by class (single block) ----------
__global__ __launch_bounds__(256) void sort_k(const int* __restrict__ opt,
                                              int* __restrict__ idxs,
                                              int* __restrict__ offs,
                                              const int* __restrict__ flags) {
  const int os = flags[1];
  __shared__ int cnt[NC], cur[NC], offl[NC + 1];
  const int t = threadIdx.x;
  if (t < NC) cnt[t] = 0;
  __syncthreads();
  for (int b = t; b < BATCH; b += 256) atomicAdd(&cnt[opt[(size_t)b * os]], 1);
  __syncthreads();
  if (t == 0) {
    int s = 0;
    for (int m = 0; m < NC; ++m) { offl[m] = s; s += cnt[m]; }
    offl[NC] = s;
  }
  __syncthreads();
  if (t < NC) cur[t] = offl[t];
  if (t <= NC) offs[t] = offl[t];
  __syncthreads();
  for (int b = t; b < BATCH; b += 256) {
    int p = atomicAdd(&cur[opt[(size_t)b * os]], 1);
    idxs[p] = b;
  }
}

// ------------- m97-style GEMM: C[M,N] = act(A[M,K] * Bt[N,K]^T + bias) ------
// 4 waves in 2x2; K-tile = 32; global_load_lds width-16 staging.
// cflag: if nonzero, C dtype follows flags[0] (f32 or bf16); else bf16.
struct GArg { const u16* A; const u16* Bt; const void* bias; void* C; int cflag; };

template <int BM, int BN, bool RELU>
__global__ __launch_bounds__(256) void gemm_bt(GArg g0, GArg g1, int M, int N, int K,
                                               const int* __restrict__ flags) {
  constexpr int WM = BM / 2, WN = BN / 2, TM = WM / 16, TN = WN / 16;
  constexpr int AISS = (BM * 32) / 2048, BISS = (BN * 32) / 2048;
  __shared__ __align__(16) u16 As[BM * 32];
  __shared__ __align__(16) u16 Bs[BN * 32];
  const GArg g = blockIdx.z ? g1 : g0;
  const int isf32 = flags[0];
  const bool cf32 = g.cflag && isf32;
  const int t = threadIdx.x;
  const int m0 = blockIdx.y * BM, n0 = blockIdx.x * BN;
  const int lane = t & 63, wid = t >> 6;
  const int wm = wid >> 1, wn = wid & 1;
  const int lr = lane & 15, lq = lane >> 4;
  const int srow = t >> 2, scol = (t & 3) * 8;   // staging: row, 8-elem chunk
  f32x4 acc[TM][TN] = {};
  for (int k0 = 0; k0 < K; k0 += 32) {
    __syncthreads();                              // prior tile's ds_reads done
#pragma unroll
    for (int s = 0; s < AISS; ++s)
      async_cp16(g.A + (size_t)(m0 + s * 64 + srow) * K + (k0 + scol),
                 &As[s * 2048 + t * 8]);
#pragma unroll
    for (int s = 0; s < BISS; ++s)
      async_cp16(g.Bt + (size_t)(n0 + s * 64 + srow) * K + (k0 + scol),
                 &Bs[s * 2048 + t * 8]);
    __syncthreads();                              // drains vmcnt before reads
    bf16x8 av[TM], bv[TN];
#pragma unroll
    for (int i = 0; i < TM; ++i)
      av[i] = *(const bf16x8*)&As[(wm * WM + i * 16 + lr) * 32 + lq * 8];
#pragma unroll
    for (int j = 0; j < TN; ++j)
      bv[j] = *(const bf16x8*)&Bs[(wn * WN + j * 16 + lr) * 32 + lq * 8];
#pragma unroll
    for (int i = 0; i < TM; ++i)
#pragma unroll
      for (int j = 0; j < TN; ++j)
        acc[i][j] = __builtin_amdgcn_mfma_f32_16x16x32_bf16(av[i], bv[j], acc[i][j], 0, 0, 0);
  }
  // epilogue: C/D layout col=lane&15, row=(lane>>4)*4+r  [m89/m91 verified]
#pragma unroll
  for (int j = 0; j < TN; ++j) {
    const int gc = n0 + wn * WN + j * 16 + lr;
    const float bval = g.bias
        ? (isf32 ? ((const float*)g.bias)[gc] : bf2f(((const u16*)g.bias)[gc]))
        : 0.f;
#pragma unroll
    for (int i = 0; i < TM; ++i) {
      const int gr = m0 + wm * WM + i * 16 + lq * 4;
#pragma unroll
      for (int r = 0; r < 4; ++r) {
        float v = acc[i][j][r] + bval;
        if (RELU) v = fmaxf(v, 0.f);
        const size_t idx = (size_t)(gr + r) * N + gc;
        if (cf32) ((float*)g.C)[idx] = v;
        else      ((u16*)g.C)[idx] = f2bf(v);
      }
    }
  }
}

// ------------- routed GEMM: outY[b] = cls_Y[b] * Y[option[b]]  --------------
// One block per (class m, 64-col tile). B-tile staged once (+8 pad -> 2-way
// banks); class rows processed in gathered 16-row MFMA chunks.
__global__ __launch_bounds__(256) void gemm_gather_y(const u16* __restrict__ clsY,
                                                     const u16* __restrict__ YT,
                                                     const int* __restrict__ idxs,
                                                     const int* __restrict__ offs,
                                                     void* __restrict__ out,
                                                     size_t out_off,
                                                     const int* __restrict__ flags) {
  const bool of32 = flags[0];
  __shared__ __align__(16) u16 Bts[64 * 264];
  __shared__ __align__(16) u16 Asm[16 * 264];
  const int m = blockIdx.y, n0 = blockIdx.x * 64, t = threadIdx.x;
  {
    const int r = t >> 2, cb = (t & 3) * 64;
    const u16* src = YT + (size_t)m * LIB * LIB + (size_t)(n0 + r) * LIB + cb;
    u16* dst = &Bts[r * 264 + cb];
#pragma unroll
    for (int v = 0; v < 8; ++v)
      *(uint4*)(dst + v * 8) = *(const uint4*)(src + v * 8);
  }
  const int start = offs[m], cnt = offs[m + 1] - start;
  const int lane = t & 63, w = t >> 6, lr = lane & 15, lq = lane >> 4;
  for (int ch = 0; ch < cnt; ch += 16) {
    __syncthreads();
    {
      const int r = t >> 4, cb = (t & 15) * 16;
      if (ch + r < cnt) {
        const u16* src = clsY + (size_t)idxs[start + ch + r] * LIB + cb;
        *(uint4*)&Asm[r * 264 + cb]     = *(const uint4*)src;
        *(uint4*)&Asm[r * 264 + cb + 8] = *(const uint4*)(src + 8);
      } else {
        uint4 z{0, 0, 0, 0};
        *(uint4*)&Asm[r * 264 + cb]     = z;
        *(uint4*)&Asm[r * 264 + cb + 8] = z;
      }
    }
    __syncthreads();
    f32x4 acc = {};
#pragma unroll
    for (int kk = 0; kk < LIB; kk += 32) {
      bf16x8 a = *(const bf16x8*)&Asm[lr * 264 + kk + lq * 8];
      bf16x8 b = *(const bf16x8*)&Bts[(w * 16 + lr) * 264 + kk + lq * 8];
      acc = __builtin_amdgcn_mfma_f32_16x16x32_bf16(a, b, acc, 0, 0, 0);
    }
#pragma unroll
    for (int r = 0; r < 4; ++r) {
      const int rowc = lq * 4 + r;
      if (ch + rowc < cnt) {
        const size_t oi = out_off + (size_t)idxs[start + ch + rowc] * LIB
                        + (n0 + w * 16 + lr);
        if (of32) ((float*)out)[oi] = acc[r];
        else      ((u16*)out)[oi] = f2bf(acc[r]);
      }
    }
  }
}

extern "C" void kernel_launch(void* const* d_in, const int* in_sizes, int n_in,
                              void* d_out, int out_size, void* d_ws, size_t ws_size,
                              hipStream_t stream) {
  const void* state  = d_in[0];
  const int*  option = (const int*)d_in[1];
  const void* embed  = d_in[2];
  const void* Wx1 = d_in[3];
  const void* bx1 = d_in[4];
  const void* Wx2 = d_in[5];
  const void* bx2 = d_in[6];
  const void* Wy1 = d_in[7];
  const void* by1 = d_in[8];
  const void* Wy2 = d_in[9];
  const void* by2 = d_in[10];
  const void* nX  = d_in[11];
  const void* nY  = d_in[12];

  char* p = (char*)d_ws;
  auto alloc = [&](size_t bytes) { char* r = p; p += (bytes + 255) & ~(size_t)255; return r; };
  int* flags = (int*)alloc(256);
  u16* all_state = (u16*)alloc((size_t)BATCH * DIN * 2);
  u16* h_x   = (u16*)alloc((size_t)BATCH * HID * 2);
  u16* h_y   = (u16*)alloc((size_t)BATCH * HID * 2);
  u16* cls_x = (u16*)alloc((size_t)BATCH * LIB * 2);
  u16* cls_y = (u16*)alloc((size_t)BATCH * LIB * 2);
  u16* WT1x  = (u16*)alloc((size_t)HID * DIN * 2);
  u16* WT1y  = (u16*)alloc((size_t)HID * DIN * 2);
  u16* WT2x  = (u16*)alloc((size_t)LIB * HID * 2);
  u16* WT2y  = (u16*)alloc((size_t)LIB * HID * 2);
  u16* XT    = (u16*)alloc((size_t)LIB * LIB * 2);
  u16* YT    = (u16*)alloc((size_t)NC * LIB * LIB * 2);
  int* idxs  = (int*)alloc((size_t)BATCH * 4);
  int* offs  = (int*)alloc((size_t)(NC + 1) * 4);

  // detection first (stream-ordered)
  detect_k<<<1, 256, 0, stream>>>((const u32*)state, (const u32*)option, flags);

  // prep
  concat_k<<<BATCH * 72 / 256, 256, 0, stream>>>(state, option, embed, all_state, flags);
  transpose_k<<<dim3(HID / 32, DIN / 32, 1),  256, 0, stream>>>(Wx1, WT1x, DIN, HID, flags);
  transpose_k<<<dim3(HID / 32, DIN / 32, 1),  256, 0, stream>>>(Wy1, WT1y, DIN, HID, flags);
  transpose_k<<<dim3(LIB / 32, HID / 32, 1),  256, 0, stream>>>(Wx2, WT2x, HID, LIB, flags);
  transpose_k<<<dim3(LIB / 32, HID / 32, 1),  256, 0, stream>>>(Wy2, WT2y, HID, LIB, flags);
  transpose_k<<<dim3(LIB / 32, LIB / 32, 1),  256, 0, stream>>>(nX, XT, LIB, LIB, flags);
  transpose_k<<<dim3(LIB / 32, LIB / 32, NC), 256, 0, stream>>>(nY, YT, LIB, LIB, flags);
  sort_k<<<1, 256, 0, stream>>>(option, idxs, offs, flags);

  // layer 1 (relu), X and Y heads via grid.z
  GArg g1x{all_state, WT1x, bx1, h_x, 0}, g1y{all_state, WT1y, by1, h_y, 0};
  gemm_bt<128, 128, true><<<dim3(HID / 128, BATCH / 128, 2), 256, 0, stream>>>(
      g1x, g1y, BATCH, HID, DIN, flags);
  // layer 2
  GArg g2x{h_x, WT2x, bx2, cls_x, 0}, g2y{h_y, WT2y, by2, cls_y, 0};
  gemm_bt<64, 64, false><<<dim3(LIB / 64, BATCH / 64, 2), 256, 0, stream>>>(
      g2x, g2y, BATCH, LIB, HID, flags);
  // noise X -> output 0 (dtype follows flag)
  GArg g3x{cls_x, XT, nullptr, d_out, 1};
  gemm_bt<64, 64, false><<<dim3(LIB / 64, BATCH / 64, 1), 256, 0, stream>>>(
      g3x, g3x, BATCH, LIB, LIB, flags);
  // noise Y (routed) -> output 1
  gemm_gather_y<<<dim3(LIB / 64, NC, 1), 256, 0, stream>>>(
      cls_y, YT, idxs, offs, d_out, (size_t)BATCH * LIB, flags);
}

// Round 3
// 196.889 us; speedup vs baseline: 1.0059x; 1.0059x over previous
//
#include <hip/hip_runtime.h>

typedef unsigned short u16;
typedef unsigned int u32;

using f32x4  = __attribute__((ext_vector_type(4))) float;
using bf16x8 = __attribute__((ext_vector_type(8))) __bf16;

#define DEV __device__ __forceinline__

DEV u16 f2bf(float f) {                       // RTNE f32 -> bf16
  union { float f; u32 u; } x; x.f = f;
  return (u16)((x.u + 0x7fffu + ((x.u >> 16) & 1u)) >> 16);
}
DEV float bf2f(u16 h) {
  union { u32 u; float f; } x; x.u = ((u32)h) << 16;
  return x.f;
}

DEV void async_cp16(const u16* g, u16* l) {   // 16B global -> LDS direct
  __builtin_amdgcn_global_load_lds((const __attribute__((address_space(1))) void*)g,
                                   (__attribute__((address_space(3))) void*)l,
                                   16, 0, 0);
}

static constexpr int BATCH = 4096;
static constexpr int FEAT  = 512;
static constexpr int EMB   = 64;
static constexpr int HID   = 1024;
static constexpr int NC    = 64;
static constexpr int DIN   = 576;   // FEAT + EMB
static constexpr int LIB   = 256;   // LIB_X == LIB_Y == OUT_J

// ---- per-block dtype / index-width self-detection (deterministic) ----------
// isf32: float tensors stored as f32 (vs bf16). ostr: option stride in u32.
DEV void detect_block(const u32* __restrict__ sraw, const u32* __restrict__ oraw,
                      int* isf32, int* ostr) {
  __shared__ int c_ib, c_onz;
  if (threadIdx.x == 0) { c_ib = 0; c_onz = 0; }
  __syncthreads();
  int ib = 0, onz = 0;
  for (int i = threadIdx.x; i < 1024; i += 256) {
    u32 w = sraw[i];
    u32 e = (w >> 7) & 0xFFu;                 // exponent of low-half-as-bf16
    if (e >= 100 && e <= 142) ib++;
    if ((i & 1) && oraw[i] != 0) onz++;
  }
  atomicAdd(&c_ib, ib);
  atomicAdd(&c_onz, onz);
  __syncthreads();
  *isf32 = (c_ib < 512) ? 1 : 0;              // low halves not bf16-like -> f32
  *ostr  = (c_onz == 0) ? 2 : 1;              // all odd words zero -> int64
}

// ---- 32x32 transpose tile (bf16-ifying): out[c][r] = in[r][c] --------------
DEV void do_transpose(const void* __restrict__ in, size_t in_off,
                      u16* __restrict__ out, int R, int C,
                      int by, int bx, int isf32) {
  __shared__ u16 tile[32][33];
  const int r0 = by * 32, c0 = bx * 32, t = threadIdx.x;
#pragma unroll
  for (int i = 0; i < 4; ++i) {
    int idx = t + i * 256, r = idx >> 5, c = idx & 31;
    size_t off = in_off + (size_t)(r0 + r) * C + (c0 + c);
    tile[r][c] = isf32 ? f2bf(((const float*)in)[off]) : ((const u16*)in)[off];
  }
  __syncthreads();
#pragma unroll
  for (int i = 0; i < 4; ++i) {
    int idx = t + i * 256, c = idx >> 5, r = idx & 31;
    out[(size_t)(c0 + c) * R + (r0 + r)] = tile[r][c];
  }
}

// ---- mega-prep: concat | 5 weight/lib transposes | YT transpose | sort -----
struct PrepArgs {
  const void *state, *emb, *Wx1, *Wy1, *Wx2, *Wy2, *nX, *nY;
  const int* opt;
  u16 *all_state, *WT1x, *WT1y, *WT2x, *WT2y, *XT, *YT;
  int *idxs, *offs, *flags;
};
static constexpr int PB_CONCAT = BATCH * 72 / 256;          // 1152
static constexpr int PB_WT1    = (DIN / 32) * (HID / 32);   // 576
static constexpr int PB_WT2    = (HID / 32) * (LIB / 32);   // 256
static constexpr int PB_XT     = (LIB / 32) * (LIB / 32);   // 64
static constexpr int PB_YT     = PB_XT * NC;                // 4096
static constexpr int PREP_BLOCKS = PB_CONCAT + 2 * PB_WT1 + 2 * PB_WT2
                                 + PB_XT + PB_YT + 1;       // 6977

__global__ __launch_bounds__(256) void prep_k(PrepArgs a) {
  int isf32, os;
  detect_block((const u32*)a.state, (const u32*)a.opt, &isf32, &os);
  int bid = blockIdx.x;
  if (bid < PB_CONCAT) {
    // concat: all_state[b] = [state[b], embed[option[b]]], 8 bf16 per thread
    int t = bid * 256 + threadIdx.x;
    int b = t / 72, ch = t % 72;
    const void* base;
    size_t srcoff;
    if (ch < 64) { base = a.state; srcoff = (size_t)b * FEAT + ch * 8; }
    else {
      base = a.emb;
      srcoff = (size_t)a.opt[(size_t)b * os] * EMB + (ch - 64) * 8;
    }
    u16 o[8];
    if (isf32) {
      const float* s = (const float*)base + srcoff;
      float4 v0 = ((const float4*)s)[0], v1 = ((const float4*)s)[1];
      o[0] = f2bf(v0.x); o[1] = f2bf(v0.y); o[2] = f2bf(v0.z); o[3] = f2bf(v0.w);
      o[4] = f2bf(v1.x); o[5] = f2bf(v1.y); o[6] = f2bf(v1.z); o[7] = f2bf(v1.w);
    } else {
      *(uint4*)o = *(const uint4*)((const u16*)base + srcoff);
    }
    *(uint4*)(a.all_state + (size_t)b * DIN + ch * 8) = *(const uint4*)o;
    return;
  }
  bid -= PB_CONCAT;
  if (bid < PB_WT1) { do_transpose(a.Wx1, 0, a.WT1x, DIN, HID, bid / 32, bid % 32, isf32); return; }
  bid -= PB_WT1;
  if (bid < PB_WT1) { do_transpose(a.Wy1, 0, a.WT1y, DIN, HID, bid / 32, bid % 32, isf32); return; }
  bid -= PB_WT1;
  if (bid < PB_WT2) { do_transpose(a.Wx2, 0, a.WT2x, HID, LIB, bid / 8, bid % 8, isf32); return; }
  bid -= PB_WT2;
  if (bid < PB_WT2) { do_transpose(a.Wy2, 0, a.WT2y, HID, LIB, bid / 8, bid % 8, isf32); return; }
  bid -= PB_WT2;
  if (bid < PB_XT) { do_transpose(a.nX, 0, a.XT, LIB, LIB, bid / 8, bid % 8, isf32); return; }
  bid -= PB_XT;
  if (bid < PB_YT) {
    int z = bid >> 6, tt = bid & 63;
    do_transpose(a.nY, (size_t)z * LIB * LIB, a.YT + (size_t)z * LIB * LIB,
                 LIB, LIB, tt / 8, tt % 8, isf32);
    return;
  }
  // last block: counting sort by class + publish flags for downstream kernels
  {
    __shared__ int cnt[NC], cur[NC], offl[NC + 1];
    const int t = threadIdx.x;
    if (t < NC) cnt[t] = 0;
    __syncthreads();
    for (int b = t; b < BATCH; b += 256) atomicAdd(&cnt[a.opt[(size_t)b * os]], 1);
    __syncthreads();
    if (t == 0) {
      int s = 0;
      for (int m = 0; m < NC; ++m) { offl[m] = s; s += cnt[m]; }
      offl[NC] = s;
    }
    __syncthreads();
    if (t < NC) cur[t] = offl[t];
    if (t <= NC) a.offs[t] = offl[t];
    __syncthreads();
    for (int b = t; b < BATCH; b += 256) {
      int p = atomicAdd(&cur[a.opt[(size_t)b * os]], 1);
      a.idxs[p] = b;
    }
    if (t == 0) { a.flags[0] = isf32; a.flags[1] = os; }
  }
}

// ------------- m97-style GEMM: C[M,N] = act(A[M,K] * Bt[N,K]^T + bias) ------
// 4 waves in 2x2; K-tile = 32; global_load_lds width-16 staging.
// cflag: if nonzero, C dtype follows flags[0] (f32 or bf16); else bf16.
struct GArg { const u16* A; const u16* Bt; const void* bias; void* C; int cflag; };

template <int BM, int BN, bool RELU>
__global__ __launch_bounds__(256) void gemm_bt(GArg g0, GArg g1, int M, int N, int K,
                                               const int* __restrict__ flags) {
  constexpr int WM = BM / 2, WN = BN / 2, TM = WM / 16, TN = WN / 16;
  constexpr int AISS = (BM * 32) / 2048, BISS = (BN * 32) / 2048;
  __shared__ __align__(16) u16 As[BM * 32];
  __shared__ __align__(16) u16 Bs[BN * 32];
  const GArg g = blockIdx.z ? g1 : g0;
  const int isf32 = flags[0];
  const bool cf32 = g.cflag && isf32;
  const int t = threadIdx.x;
  const int m0 = blockIdx.y * BM, n0 = blockIdx.x * BN;
  const int lane = t & 63, wid = t >> 6;
  const int wm = wid >> 1, wn = wid & 1;
  const int lr = lane & 15, lq = lane >> 4;
  const int srow = t >> 2, scol = (t & 3) * 8;   // staging: row, 8-elem chunk
  f32x4 acc[TM][TN] = {};
  for (int k0 = 0; k0 < K; k0 += 32) {
    __syncthreads();                              // prior tile's ds_reads done
#pragma unroll
    for (int s = 0; s < AISS; ++s)
      async_cp16(g.A + (size_t)(m0 + s * 64 + srow) * K + (k0 + scol),
                 &As[s * 2048 + t * 8]);
#pragma unroll
    for (int s = 0; s < BISS; ++s)
      async_cp16(g.Bt + (size_t)(n0 + s * 64 + srow) * K + (k0 + scol),
                 &Bs[s * 2048 + t * 8]);
    __syncthreads();                              // drains vmcnt before reads
    bf16x8 av[TM], bv[TN];
#pragma unroll
    for (int i = 0; i < TM; ++i)
      av[i] = *(const bf16x8*)&As[(wm * WM + i * 16 + lr) * 32 + lq * 8];
#pragma unroll
    for (int j = 0; j < TN; ++j)
      bv[j] = *(const bf16x8*)&Bs[(wn * WN + j * 16 + lr) * 32 + lq * 8];
#pragma unroll
    for (int i = 0; i < TM; ++i)
#pragma unroll
      for (int j = 0; j < TN; ++j)
        acc[i][j] = __builtin_amdgcn_mfma_f32_16x16x32_bf16(av[i], bv[j], acc[i][j], 0, 0, 0);
  }
  // epilogue: C/D layout col=lane&15, row=(lane>>4)*4+r  [m89/m91 verified]
#pragma unroll
  for (int j = 0; j < TN; ++j) {
    const int gc = n0 + wn * WN + j * 16 + lr;
    const float bval = g.bias
        ? (isf32 ? ((const float*)g.bias)[gc] : bf2f(((const u16*)g.bias)[gc]))
        : 0.f;
#pragma unroll
    for (int i = 0; i < TM; ++i) {
      const int gr = m0 + wm * WM + i * 16 + lq * 4;
#pragma unroll
      for (int r = 0; r < 4; ++r) {
        float v = acc[i][j][r] + bval;
        if (RELU) v = fmaxf(v, 0.f);
        const size_t idx = (size_t)(gr + r) * N + gc;
        if (cf32) ((float*)g.C)[idx] = v;
        else      ((u16*)g.C)[idx] = f2bf(v);
      }
    }
  }
}

// ------------- routed GEMM: outY[b] = cls_Y[b] * Y[option[b]]  --------------
// One block per (class m, 64-col tile). B-tile staged once (+8 pad -> 2-way
// banks); class rows processed in gathered 16-row MFMA chunks.
__global__ __launch_bounds__(256) void gemm_gather_y(const u16* __restrict__ clsY,
                                                     const u16* __restrict__ YT,
                                                     const int* __restrict__ idxs,
                                                     const int* __restrict__ offs,
                                                     void* __restrict__ out,
                                                     size_t out_off,
                                                     const int* __restrict__ flags) {
  const bool of32 = flags[0];
  __shared__ __align__(16) u16 Bts[64 * 264];
  __shared__ __align__(16) u16 Asm[16 * 264];
  const int m = blockIdx.y, n0 = blockIdx.x * 64, t = threadIdx.x;
  {
    const int r = t >> 2, cb = (t & 3) * 64;
    const u16* src = YT + (size_t)m * LIB * LIB + (size_t)(n0 + r) * LIB + cb;
    u16* dst = &Bts[r * 264 + cb];
#pragma unroll
    for (int v = 0; v < 8; ++v)
      *(uint4*)(dst + v * 8) = *(const uint4*)(src + v * 8);
  }
  const int start = offs[m], cnt = offs[m + 1] - start;
  const int lane = t & 63, w = t >> 6, lr = lane & 15, lq = lane >> 4;
  for (int ch = 0; ch < cnt; ch += 16) {
    __syncthreads();
    {
      const int r = t >> 4, cb = (t & 15) * 16;
      if (ch + r < cnt) {
        const u16* src = clsY + (size_t)idxs[start + ch + r] * LIB + cb;
        *(uint4*)&Asm[r * 264 + cb]     = *(const uint4*)src;
        *(uint4*)&Asm[r * 264 + cb + 8] = *(const uint4*)(src + 8);
      } else {
        uint4 z{0, 0, 0, 0};
        *(uint4*)&Asm[r * 264 + cb]     = z;
        *(uint4*)&Asm[r * 264 + cb + 8] = z;
      }
    }
    __syncthreads();
    f32x4 acc = {};
#pragma unroll
    for (int kk = 0; kk < LIB; kk += 32) {
      bf16x8 a = *(const bf16x8*)&Asm[lr * 264 + kk + lq * 8];
      bf16x8 b = *(const bf16x8*)&Bts[(w * 16 + lr) * 264 + kk + lq * 8];
      acc = __builtin_amdgcn_mfma_f32_16x16x32_bf16(a, b, acc, 0, 0, 0);
    }
#pragma unroll
    for (int r = 0; r < 4; ++r) {
      const int rowc = lq * 4 + r;
      if (ch + rowc < cnt) {
        const size_t oi = out_off + (size_t)idxs[start + ch + rowc] * LIB
                        + (n0 + w * 16 + lr);
        if (of32) ((float*)out)[oi] = acc[r];
        else      ((u16*)out)[oi] = f2bf(acc[r]);
      }
    }
  }
}

extern "C" void kernel_launch(void* const* d_in, const int* in_sizes, int n_in,
                              void* d_out, int out_size, void* d_ws, size_t ws_size,
                              hipStream_t stream) {
  char* p = (char*)d_ws;
  auto alloc = [&](size_t bytes) { char* r = p; p += (bytes + 255) & ~(size_t)255; return r; };
  int* flags = (int*)alloc(256);
  u16* all_state = (u16*)alloc((size_t)BATCH * DIN * 2);
  u16* h_x   = (u16*)alloc((size_t)BATCH * HID * 2);
  u16* h_y   = (u16*)alloc((size_t)BATCH * HID * 2);
  u16* cls_x = (u16*)alloc((size_t)BATCH * LIB * 2);
  u16* cls_y = (u16*)alloc((size_t)BATCH * LIB * 2);
  u16* WT1x  = (u16*)alloc((size_t)HID * DIN * 2);
  u16* WT1y  = (u16*)alloc((size_t)HID * DIN * 2);
  u16* WT2x  = (u16*)alloc((size_t)LIB * HID * 2);
  u16* WT2y  = (u16*)alloc((size_t)LIB * HID * 2);
  u16* XT    = (u16*)alloc((size_t)LIB * LIB * 2);
  u16* YT    = (u16*)alloc((size_t)NC * LIB * LIB * 2);
  int* idxs  = (int*)alloc((size_t)BATCH * 4);
  int* offs  = (int*)alloc((size_t)(NC + 1) * 4);

  PrepArgs pa;
  pa.state = d_in[0]; pa.opt = (const int*)d_in[1]; pa.emb = d_in[2];
  pa.Wx1 = d_in[3]; pa.Wx2 = d_in[5]; pa.Wy1 = d_in[7]; pa.Wy2 = d_in[9];
  pa.nX = d_in[11]; pa.nY = d_in[12];
  pa.all_state = all_state; pa.WT1x = WT1x; pa.WT1y = WT1y;
  pa.WT2x = WT2x; pa.WT2y = WT2y; pa.XT = XT; pa.YT = YT;
  pa.idxs = idxs; pa.offs = offs; pa.flags = flags;

  // 1) all prep concurrently in one launch
  prep_k<<<PREP_BLOCKS, 256, 0, stream>>>(pa);

  // 2) layer 1 (relu), X and Y heads via grid.z
  GArg g1x{all_state, WT1x, d_in[4], h_x, 0}, g1y{all_state, WT1y, d_in[8], h_y, 0};
  gemm_bt<128, 128, true><<<dim3(HID / 128, BATCH / 128, 2), 256, 0, stream>>>(
      g1x, g1y, BATCH, HID, DIN, flags);

  // 3) layer 2, 128x64 tiles (256 blocks)
  GArg g2x{h_x, WT2x, d_in[6], cls_x, 0}, g2y{h_y, WT2y, d_in[10], cls_y, 0};
  gemm_bt<128, 64, false><<<dim3(LIB / 64, BATCH / 128, 2), 256, 0, stream>>>(
      g2x, g2y, BATCH, LIB, HID, flags);

  // 4) noise X -> output 0 (dtype follows flag)
  GArg g3x{cls_x, XT, nullptr, d_out, 1};
  gemm_bt<64, 64, false><<<dim3(LIB / 64, BATCH / 64, 1), 256, 0, stream>>>(
      g3x, g3x, BATCH, LIB, LIB, flags);

  // 5) noise Y (routed) -> output 1
  gemm_gather_y<<<dim3(LIB / 64, NC, 1), 256, 0, stream>>>(
      cls_y, YT, idxs, offs, d_out, (size_t)BATCH * LIB, flags);
}

// Round 4
// 157.904 us; speedup vs baseline: 1.2542x; 1.2469x over previous
//
#include <hip/hip_runtime.h>

typedef unsigned short u16;
typedef unsigned int u32;

using f32x4  = __attribute__((ext_vector_type(4))) float;
using bf16x8 = __attribute__((ext_vector_type(8))) __bf16;

#define DEV __device__ __forceinline__

DEV u16 f2bf(float f) {                       // RTNE f32 -> bf16
  union { float f; u32 u; } x; x.f = f;
  return (u16)((x.u + 0x7fffu + ((x.u >> 16) & 1u)) >> 16);
}
DEV float bf2f(u16 h) {
  union { u32 u; float f; } x; x.u = ((u32)h) << 16;
  return x.f;
}

DEV void async_cp16(const u16* g, u16* l) {   // 16B global -> LDS direct
  __builtin_amdgcn_global_load_lds((const __attribute__((address_space(1))) void*)g,
                                   (__attribute__((address_space(3))) void*)l,
                                   16, 0, 0);
}

static constexpr int BATCH = 4096;
static constexpr int FEAT  = 512;
static constexpr int EMB   = 64;
static constexpr int HID   = 1024;
static constexpr int NC    = 64;
static constexpr int DIN   = 576;   // FEAT + EMB
static constexpr int LIB   = 256;   // LIB_X == LIB_Y == OUT_J

// ---- cheap per-block dtype / index-width detection (1 load/thread) ---------
// n=256 samples: bf16 storage -> ~256 exponents in [100,142]; f32 storage ->
// low-half-as-bf16 exponent is mantissa bits, ~17% in band (E=43). Threshold
// 128 gives astronomically safe margins. option: int64 -> all odd u32 words
// zero; int32 -> P(128 random 0..63 all zero) = 64^-128.
DEV void detect_lite(const u32* __restrict__ sraw, const u32* __restrict__ oraw,
                     int* isf32, int* ostr) {
  __shared__ int cib, conz;
  const int t = threadIdx.x;
  if (t == 0) { cib = 0; conz = 0; }
  u32 w = sraw[t];
  u32 e = (w >> 7) & 0xFFu;
  unsigned long long m1 = __ballot(e >= 100 && e <= 142);
  unsigned long long m2 = __ballot((t & 1) && oraw[t] != 0);
  __syncthreads();
  if ((t & 63) == 0) {
    atomicAdd(&cib, __popcll(m1));
    atomicAdd(&conz, __popcll(m2));
  }
  __syncthreads();
  *isf32 = (cib < 128) ? 1 : 0;
  *ostr  = (conz == 0) ? 2 : 1;
}

// ---- 64x64 transpose tile (bf16-ifying), fully vectorized ------------------
// load: 16 elems/thread (4xfloat4 or 2xuint4); store: 16 transposed elems as
// 2xuint4. LDS rows padded to 72 u16 (store-phase reads: 2 lanes/word, free).
DEV void do_transpose64(const void* __restrict__ in, size_t in_off,
                        u16* __restrict__ out, int R, int C,
                        int by, int bx, int isf32) {
  __shared__ u16 tile[64 * 72];
  const int t = threadIdx.x;
  {
    const int r = t >> 2, c0 = (t & 3) * 16;
    size_t off = in_off + (size_t)(by * 64 + r) * C + (bx * 64 + c0);
    u16 v[16];
    if (isf32) {
      const float4* s = (const float4*)((const float*)in + off);
      float4 a0 = s[0], a1 = s[1], a2 = s[2], a3 = s[3];
      v[0] = f2bf(a0.x); v[1] = f2bf(a0.y); v[2]  = f2bf(a0.z); v[3]  = f2bf(a0.w);
      v[4] = f2bf(a1.x); v[5] = f2bf(a1.y); v[6]  = f2bf(a1.z); v[7]  = f2bf(a1.w);
      v[8] = f2bf(a2.x); v[9] = f2bf(a2.y); v[10] = f2bf(a2.z); v[11] = f2bf(a2.w);
      v[12] = f2bf(a3.x); v[13] = f2bf(a3.y); v[14] = f2bf(a3.z); v[15] = f2bf(a3.w);
    } else {
      const uint4* s = (const uint4*)((const u16*)in + off);
      *(uint4*)&v[0] = s[0];
      *(uint4*)&v[8] = s[1];
    }
    *(uint4*)&tile[r * 72 + c0]     = *(uint4*)&v[0];
    *(uint4*)&tile[r * 72 + c0 + 8] = *(uint4*)&v[8];
  }
  __syncthreads();
  {
    const int c = t & 63, rs = (t >> 6) * 16;
    u16 w[16];
#pragma unroll
    for (int i = 0; i < 16; ++i) w[i] = tile[(rs + i) * 72 + c];
    size_t oo = (size_t)(bx * 64 + c) * R + (by * 64 + rs);
    *(uint4*)&out[oo]     = *(uint4*)&w[0];
    *(uint4*)&out[oo + 8] = *(uint4*)&w[8];
  }
}

// ---- mega-prep: sort | concat | 5 weight/lib transposes | YT transpose -----
struct PrepArgs {
  const void *state, *emb, *Wx1, *Wy1, *Wx2, *Wy2, *nX, *nY;
  const int* opt;
  u16 *all_state, *WT1x, *WT1y, *WT2x, *WT2y, *XT, *YT;
  int *idxs, *offs, *flags;
};
static constexpr int PB_CONCAT = BATCH * 36 / 256;                    // 576
static constexpr int PB_WT1 = (DIN / 64) * (HID / 64);                // 144
static constexpr int PB_WT2 = (HID / 64) * (LIB / 64);                // 64
static constexpr int PB_XT  = (LIB / 64) * (LIB / 64);                // 16
static constexpr int PB_YT  = PB_XT * NC;                             // 1024
static constexpr int PREP_BLOCKS = 1 + PB_CONCAT + 2 * PB_WT1 + 2 * PB_WT2
                                 + PB_XT + PB_YT;                     // 2033

__global__ __launch_bounds__(256) void prep_k(PrepArgs a) {
  int isf32, os;
  detect_lite((const u32*)a.state, (const u32*)a.opt, &isf32, &os);
  int bid = blockIdx.x;
  if (bid == 0) {
    // counting sort by class + publish flags for downstream kernels
    __shared__ int cnt[NC], cur[NC], offl[NC + 1];
    const int t = threadIdx.x;
    if (t < NC) cnt[t] = 0;
    __syncthreads();
    for (int b = t; b < BATCH; b += 256) atomicAdd(&cnt[a.opt[(size_t)b * os]], 1);
    __syncthreads();
    if (t == 0) {
      int s = 0;
      for (int m = 0; m < NC; ++m) { offl[m] = s; s += cnt[m]; }
      offl[NC] = s;
    }
    __syncthreads();
    if (t < NC) cur[t] = offl[t];
    if (t <= NC) a.offs[t] = offl[t];
    __syncthreads();
    for (int b = t; b < BATCH; b += 256) {
      int p = atomicAdd(&cur[a.opt[(size_t)b * os]], 1);
      a.idxs[p] = b;
    }
    if (t == 0) { a.flags[0] = isf32; a.flags[1] = os; }
    return;
  }
  bid -= 1;
  if (bid < PB_CONCAT) {
    // concat: all_state[b] = [state[b], embed[option[b]]], 16 bf16/thread
    int t = bid * 256 + threadIdx.x;
    int b = t / 36, ch = t % 36;
    const void* base;
    size_t srcoff;
    if (ch < 32) { base = a.state; srcoff = (size_t)b * FEAT + ch * 16; }
    else {
      base = a.emb;
      srcoff = (size_t)a.opt[(size_t)b * os] * EMB + (ch - 32) * 16;
    }
    u16 o[16];
    if (isf32) {
      const float4* s = (const float4*)((const float*)base + srcoff);
      float4 a0 = s[0], a1 = s[1], a2 = s[2], a3 = s[3];
      o[0] = f2bf(a0.x); o[1] = f2bf(a0.y); o[2]  = f2bf(a0.z); o[3]  = f2bf(a0.w);
      o[4] = f2bf(a1.x); o[5] = f2bf(a1.y); o[6]  = f2bf(a1.z); o[7]  = f2bf(a1.w);
      o[8] = f2bf(a2.x); o[9] = f2bf(a2.y); o[10] = f2bf(a2.z); o[11] = f2bf(a2.w);
      o[12] = f2bf(a3.x); o[13] = f2bf(a3.y); o[14] = f2bf(a3.z); o[15] = f2bf(a3.w);
    } else {
      const uint4* s = (const uint4*)((const u16*)base + srcoff);
      *(uint4*)&o[0] = s[0];
      *(uint4*)&o[8] = s[1];
    }
    u16* dst = a.all_state + (size_t)b * DIN + ch * 16;
    *(uint4*)dst       = *(const uint4*)&o[0];
    *(uint4*)(dst + 8) = *(const uint4*)&o[8];
    return;
  }
  bid -= PB_CONCAT;
  if (bid < PB_WT1) { do_transpose64(a.Wx1, 0, a.WT1x, DIN, HID, bid >> 4, bid & 15, isf32); return; }
  bid -= PB_WT1;
  if (bid < PB_WT1) { do_transpose64(a.Wy1, 0, a.WT1y, DIN, HID, bid >> 4, bid & 15, isf32); return; }
  bid -= PB_WT1;
  if (bid < PB_WT2) { do_transpose64(a.Wx2, 0, a.WT2x, HID, LIB, bid >> 2, bid & 3, isf32); return; }
  bid -= PB_WT2;
  if (bid < PB_WT2) { do_transpose64(a.Wy2, 0, a.WT2y, HID, LIB, bid >> 2, bid & 3, isf32); return; }
  bid -= PB_WT2;
  if (bid < PB_XT) { do_transpose64(a.nX, 0, a.XT, LIB, LIB, bid >> 2, bid & 3, isf32); return; }
  bid -= PB_XT;
  {
    int z = bid >> 4, tt = bid & 15;
    do_transpose64(a.nY, (size_t)z * LIB * LIB, a.YT + (size_t)z * LIB * LIB,
                   LIB, LIB, tt >> 2, tt & 3, isf32);
  }
}

// ------------- m97-style GEMM: C[M,N] = act(A[M,K] * Bt[N,K]^T + bias) ------
struct GArg { const u16* A; const u16* Bt; const void* bias; void* C; int cflag; };

template <int BM, int BN, bool RELU>
__global__ __launch_bounds__(256) void gemm_bt(GArg g0, GArg g1, int M, int N, int K,
                                               const int* __restrict__ flags) {
  constexpr int WM = BM / 2, WN = BN / 2, TM = WM / 16, TN = WN / 16;
  constexpr int AISS = (BM * 32) / 2048, BISS = (BN * 32) / 2048;
  __shared__ __align__(16) u16 As[BM * 32];
  __shared__ __align__(16) u16 Bs[BN * 32];
  const GArg g = blockIdx.z ? g1 : g0;
  const int isf32 = flags[0];
  const bool cf32 = g.cflag && isf32;
  const int t = threadIdx.x;
  const int m0 = blockIdx.y * BM, n0 = blockIdx.x * BN;
  const int lane = t & 63, wid = t >> 6;
  const int wm = wid >> 1, wn = wid & 1;
  const int lr = lane & 15, lq = lane >> 4;
  const int srow = t >> 2, scol = (t & 3) * 8;
  f32x4 acc[TM][TN] = {};
  for (int k0 = 0; k0 < K; k0 += 32) {
    __syncthreads();
#pragma unroll
    for (int s = 0; s < AISS; ++s)
      async_cp16(g.A + (size_t)(m0 + s * 64 + srow) * K + (k0 + scol),
                 &As[s * 2048 + t * 8]);
#pragma unroll
    for (int s = 0; s < BISS; ++s)
      async_cp16(g.Bt + (size_t)(n0 + s * 64 + srow) * K + (k0 + scol),
                 &Bs[s * 2048 + t * 8]);
    __syncthreads();
    bf16x8 av[TM], bv[TN];
#pragma unroll
    for (int i = 0; i < TM; ++i)
      av[i] = *(const bf16x8*)&As[(wm * WM + i * 16 + lr) * 32 + lq * 8];
#pragma unroll
    for (int j = 0; j < TN; ++j)
      bv[j] = *(const bf16x8*)&Bs[(wn * WN + j * 16 + lr) * 32 + lq * 8];
#pragma unroll
    for (int i = 0; i < TM; ++i)
#pragma unroll
      for (int j = 0; j < TN; ++j)
        acc[i][j] = __builtin_amdgcn_mfma_f32_16x16x32_bf16(av[i], bv[j], acc[i][j], 0, 0, 0);
  }
#pragma unroll
  for (int j = 0; j < TN; ++j) {
    const int gc = n0 + wn * WN + j * 16 + lr;
    const float bval = g.bias
        ? (isf32 ? ((const float*)g.bias)[gc] : bf2f(((const u16*)g.bias)[gc]))
        : 0.f;
#pragma unroll
    for (int i = 0; i < TM; ++i) {
      const int gr = m0 + wm * WM + i * 16 + lq * 4;
#pragma unroll
      for (int r = 0; r < 4; ++r) {
        float v = acc[i][j][r] + bval;
        if (RELU) v = fmaxf(v, 0.f);
        const size_t idx = (size_t)(gr + r) * N + gc;
        if (cf32) ((float*)g.C)[idx] = v;
        else      ((u16*)g.C)[idx] = f2bf(v);
      }
    }
  }
}

// ------------- tail: blocks 0..255 = noiseX gemm; 256..511 = routed gatherY -
struct TailArgs {
  const u16 *cls_x, *XT, *cls_y, *YT;
  const int *idxs, *offs, *flags;
  void* out;            // out0 at 0, out1 at BATCH*LIB
};

__global__ __launch_bounds__(256) void tail_k(TailArgs a) {
  __shared__ __align__(16) u16 Bts[64 * 264];   // gather B-tile / gemm As+Bs
  __shared__ __align__(16) u16 Asm[16 * 264];
  const bool of32 = a.flags[0];
  const int t = threadIdx.x;
  const int lane = t & 63, w = t >> 6, lr = lane & 15, lq = lane >> 4;

  if (blockIdx.x < 256) {
    // ---- noiseX: 64x64 bt-gemm, C = cls_x[4096,256] * XT[256,256]^T -------
    u16* As = Bts;            // 64*32
    u16* Bs = Bts + 2048;     // 64*32
    const int m0 = (blockIdx.x >> 2) * 64, n0 = (blockIdx.x & 3) * 64;
    const int wm = w >> 1, wn = w & 1;
    const int srow = t >> 2, scol = (t & 3) * 8;
    f32x4 acc[2][2] = {};
    for (int k0 = 0; k0 < LIB; k0 += 32) {
      __syncthreads();
      async_cp16(a.cls_x + (size_t)(m0 + srow) * LIB + (k0 + scol), &As[t * 8]);
      async_cp16(a.XT    + (size_t)(n0 + srow) * LIB + (k0 + scol), &Bs[t * 8]);
      __syncthreads();
      bf16x8 av[2], bv[2];
#pragma unroll
      for (int i = 0; i < 2; ++i)
        av[i] = *(const bf16x8*)&As[(wm * 32 + i * 16 + lr) * 32 + lq * 8];
#pragma unroll
      for (int j = 0; j < 2; ++j)
        bv[j] = *(const bf16x8*)&Bs[(wn * 32 + j * 16 + lr) * 32 + lq * 8];
#pragma unroll
      for (int i = 0; i < 2; ++i)
#pragma unroll
        for (int j = 0; j < 2; ++j)
          acc[i][j] = __builtin_amdgcn_mfma_f32_16x16x32_bf16(av[i], bv[j], acc[i][j], 0, 0, 0);
    }
#pragma unroll
    for (int j = 0; j < 2; ++j) {
      const int gc = n0 + (w & 1) * 32 + j * 16 + lr;
#pragma unroll
      for (int i = 0; i < 2; ++i) {
        const int gr = m0 + (w >> 1) * 32 + i * 16 + lq * 4;
#pragma unroll
        for (int r = 0; r < 4; ++r) {
          const size_t idx = (size_t)(gr + r) * LIB + gc;
          if (of32) ((float*)a.out)[idx] = acc[i][j][r];
          else      ((u16*)a.out)[idx] = f2bf(acc[i][j][r]);
        }
      }
    }
    return;
  }

  // ---- routed gatherY: one block per (class m, 64-col tile) ----------------
  const int bid = blockIdx.x - 256;
  const int m = bid >> 2, n0 = (bid & 3) * 64;
  {
    const int r = t >> 2, cb = (t & 3) * 64;
    const u16* src = a.YT + (size_t)m * LIB * LIB + (size_t)(n0 + r) * LIB + cb;
    u16* dst = &Bts[r * 264 + cb];
#pragma unroll
    for (int v = 0; v < 8; ++v)
      *(uint4*)(dst + v * 8) = *(const uint4*)(src + v * 8);
  }
  const int start = a.offs[m], cnt = a.offs[m + 1] - start;
  const size_t out_off = (size_t)BATCH * LIB;
  for (int ch = 0; ch < cnt; ch += 16) {
    __syncthreads();
    {
      const int r = t >> 4, cb = (t & 15) * 16;
      if (ch + r < cnt) {
        const u16* src = a.cls_y + (size_t)a.idxs[start + ch + r] * LIB + cb;
        *(uint4*)&Asm[r * 264 + cb]     = *(const uint4*)src;
        *(uint4*)&Asm[r * 264 + cb + 8] = *(const uint4*)(src + 8);
      } else {
        uint4 z{0, 0, 0, 0};
        *(uint4*)&Asm[r * 264 + cb]     = z;
        *(uint4*)&Asm[r * 264 + cb + 8] = z;
      }
    }
    __syncthreads();
    f32x4 acc = {};
#pragma unroll
    for (int kk = 0; kk < LIB; kk += 32) {
      bf16x8 av = *(const bf16x8*)&Asm[lr * 264 + kk + lq * 8];
      bf16x8 bv = *(const bf16x8*)&Bts[(w * 16 + lr) * 264 + kk + lq * 8];
      acc = __builtin_amdgcn_mfma_f32_16x16x32_bf16(av, bv, acc, 0, 0, 0);
    }
#pragma unroll
    for (int r = 0; r < 4; ++r) {
      const int rowc = lq * 4 + r;
      if (ch + rowc < cnt) {
        const size_t oi = out_off + (size_t)a.idxs[start + ch + rowc] * LIB
                        + (n0 + w * 16 + lr);
        if (of32) ((float*)a.out)[oi] = acc[r];
        else      ((u16*)a.out)[oi] = f2bf(acc[r]);
      }
    }
  }
}

extern "C" void kernel_launch(void* const* d_in, const int* in_sizes, int n_in,
                              void* d_out, int out_size, void* d_ws, size_t ws_size,
                              hipStream_t stream) {
  char* p = (char*)d_ws;
  auto alloc = [&](size_t bytes) { char* r = p; p += (bytes + 255) & ~(size_t)255; return r; };
  int* flags = (int*)alloc(256);
  u16* all_state = (u16*)alloc((size_t)BATCH * DIN * 2);
  u16* h_x   = (u16*)alloc((size_t)BATCH * HID * 2);
  u16* h_y   = (u16*)alloc((size_t)BATCH * HID * 2);
  u16* cls_x = (u16*)alloc((size_t)BATCH * LIB * 2);
  u16* cls_y = (u16*)alloc((size_t)BATCH * LIB * 2);
  u16* WT1x  = (u16*)alloc((size_t)HID * DIN * 2);
  u16* WT1y  = (u16*)alloc((size_t)HID * DIN * 2);
  u16* WT2x  = (u16*)alloc((size_t)LIB * HID * 2);
  u16* WT2y  = (u16*)alloc((size_t)LIB * HID * 2);
  u16* XT    = (u16*)alloc((size_t)LIB * LIB * 2);
  u16* YT    = (u16*)alloc((size_t)NC * LIB * LIB * 2);
  int* idxs  = (int*)alloc((size_t)BATCH * 4);
  int* offs  = (int*)alloc((size_t)(NC + 1) * 4);

  PrepArgs pa;
  pa.state = d_in[0]; pa.opt = (const int*)d_in[1]; pa.emb = d_in[2];
  pa.Wx1 = d_in[3]; pa.Wx2 = d_in[5]; pa.Wy1 = d_in[7]; pa.Wy2 = d_in[9];
  pa.nX = d_in[11]; pa.nY = d_in[12];
  pa.all_state = all_state; pa.WT1x = WT1x; pa.WT1y = WT1y;
  pa.WT2x = WT2x; pa.WT2y = WT2y; pa.XT = XT; pa.YT = YT;
  pa.idxs = idxs; pa.offs = offs; pa.flags = flags;

  // 1) all prep concurrently in one launch (vectorized 64x64 tiles)
  prep_k<<<PREP_BLOCKS, 256, 0, stream>>>(pa);

  // 2) layer 1 (relu), X and Y heads via grid.z
  GArg g1x{all_state, WT1x, d_in[4], h_x, 0}, g1y{all_state, WT1y, d_in[8], h_y, 0};
  gemm_bt<128, 128, true><<<dim3(HID / 128, BATCH / 128, 2), 256, 0, stream>>>(
      g1x, g1y, BATCH, HID, DIN, flags);

  // 3) layer 2, 64x64 tiles (512 blocks -> 2 blocks/CU co-residency)
  GArg g2x{h_x, WT2x, d_in[6], cls_x, 0}, g2y{h_y, WT2y, d_in[10], cls_y, 0};
  gemm_bt<64, 64, false><<<dim3(LIB / 64, BATCH / 64, 2), 256, 0, stream>>>(
      g2x, g2y, BATCH, LIB, HID, flags);

  // 4) merged tail: noiseX gemm (256 blocks) + routed gatherY (256 blocks)
  TailArgs ta{cls_x, XT, cls_y, YT, idxs, offs, flags, d_out};
  tail_k<<<512, 256, 0, stream>>>(ta);
}